// Round 1
// baseline (930.419 us; speedup 1.0000x reference)
//
#include <hip/hip_runtime.h>
#include <math.h>

// Problem dims (fixed by reference)
#define N_S 50000
#define C_C 2000
#define D_D 128
#define K_K 8
#define U_U 20000

#define QGRID 512   // k_q blocks: 2 blocks/CU for latency hiding

// ws layout (float offsets)
#define WS_Q      0          // 16000 floats: Q[c*8+k]
#define WS_P      16384      // 1024: UA online-softmax partials [64 blocks][8 k][m,s]
#define WS_MK     17408      // 8: per-k max of UA column
#define WS_ISK    17416      // 8: per-k 1/sumexp of UA column
#define WS_M      17472      // 16000: per-(c,k) max over d of CA
#define WS_IS     33472      // 16000: per-(c,k) 1/sumexp
#define WS_A      49472      // 400000: A[n*8+k]

// ---------------------------------------------------------------------------
// K1a: online column-softmax partials of UA (softmax over U per k), plus zero Q
// grid 64 x 256
__global__ __launch_bounds__(256) void k_ua_part(const float* __restrict__ UA,
                                                 float* __restrict__ ws) {
  int t = threadIdx.x, b = blockIdx.x;
  int gid = b * 256 + t;
  if (gid < C_C * K_K) ws[WS_Q + gid] = 0.f;   // zero Q for atomics
  int k = gid & 7;
  float m = -INFINITY, s = 0.f;
  for (int u = (gid >> 3); u < U_U; u += 2048) {
    float v = UA[u * 8 + k];                    // addr = gid + 16384*i: coalesced
    if (v > m) { s = s * __expf(m - v) + 1.f; m = v; }
    else       { s += __expf(v - m); }
  }
  // merge same-k lanes within wave (k = lane&7): xor offsets 8,16,32
  #pragma unroll
  for (int off = 8; off <= 32; off <<= 1) {
    float om = __shfl_xor(m, off);
    float os = __shfl_xor(s, off);
    float M = fmaxf(m, om);
    s = s * __expf(m - M) + os * __expf(om - M);
    m = M;
  }
  __shared__ float sm[32], ss_[32];             // 4 waves x 8 k
  int l = t & 63, wid = t >> 6;
  if (l < 8) { sm[wid * 8 + l] = m; ss_[wid * 8 + l] = s; }
  __syncthreads();
  if (t < 8) {
    float M = sm[t], S = ss_[t];
    #pragma unroll
    for (int w = 1; w < 4; w++) {
      float om = sm[w * 8 + t], os = ss_[w * 8 + t];
      float MM = fmaxf(M, om);
      S = S * __expf(M - MM) + os * __expf(om - MM);
      M = MM;
    }
    ws[WS_P + b * 16 + t * 2]     = M;
    ws[WS_P + b * 16 + t * 2 + 1] = S;
  }
}

// K1b: final merge of 64 UA partials -> m_k, 1/s_k.  grid 1 x 64
__global__ __launch_bounds__(64) void k_ua_final(float* __restrict__ ws) {
  int t = threadIdx.x;
  if (t >= 8) return;
  float M = -INFINITY, S = 0.f;
  for (int b = 0; b < 64; b++) {
    float om = ws[WS_P + b * 16 + t * 2], os = ws[WS_P + b * 16 + t * 2 + 1];
    float MM = fmaxf(M, om);
    S = S * __expf(M - MM) + os * __expf(om - MM);
    M = MM;
  }
  ws[WS_MK + t]  = M;
  ws[WS_ISK + t] = 1.f / S;
}

// ---------------------------------------------------------------------------
// K3: per-(c,k) softmax stats of CA over d (len 128, stride 8 elems).
// One wave per (c,k). grid 4000 x 256
__global__ __launch_bounds__(256) void k_ca_stats(const float* __restrict__ CA,
                                                  float* __restrict__ ws) {
  int t = threadIdx.x;
  int wid = t >> 6, l = t & 63;
  int p = blockIdx.x * 4 + wid;                 // < 16000
  int c = p >> 3, k = p & 7;
  const float* row = CA + (size_t)c * 1024;
  float v0 = row[l * 8 + k];
  float v1 = row[(l + 64) * 8 + k];
  float m = fmaxf(v0, v1);
  #pragma unroll
  for (int off = 1; off <= 32; off <<= 1) m = fmaxf(m, __shfl_xor(m, off));
  float s = __expf(v0 - m) + __expf(v1 - m);
  #pragma unroll
  for (int off = 1; off <= 32; off <<= 1) s += __shfl_xor(s, off);
  if (l == 0) { ws[WS_M + p] = m; ws[WS_IS + p] = 1.f / s; }
}

// ---------------------------------------------------------------------------
// K4: A[n,k] = (1/s_ck) * sum_d X[n,d]*exp(CA[c,d,k]-m_ck), c=cour[n].
// One wave per sample; lane = (dgroup<<3)|k so CA reads are fully coalesced.
// grid 12500 x 256
__global__ __launch_bounds__(256) void k_act(const float* __restrict__ X,
                                             const int* __restrict__ cour,
                                             const float* __restrict__ CA,
                                             float* __restrict__ ws) {
  int t = threadIdx.x;
  int wid = t >> 6, l = t & 63;
  int n = blockIdx.x * 4 + wid;                 // exactly 50000
  int c = cour[n];
  int k = l & 7, dg = l >> 3;
  float mK  = ws[WS_M + c * 8 + k];
  float isK = ws[WS_IS + c * 8 + k];
  const float* carow = CA + (size_t)c * 1024;
  const float* xrow  = X + (size_t)n * 128;
  float acc = 0.f;
  #pragma unroll
  for (int j = 0; j < 16; j++) {
    float v = carow[l + 64 * j];                // 64 consecutive floats / wave-step
    float x = xrow[dg + 8 * j];
    acc += x * __expf(v - mK);
  }
  acc += __shfl_xor(acc, 8);
  acc += __shfl_xor(acc, 16);
  acc += __shfl_xor(acc, 32);
  if (l < 8) ws[WS_A + n * 8 + l] = acc * isK;  // lane l holds k=l
}

// ---------------------------------------------------------------------------
// K2: fused UC row-softmax + Q accumulation. One block per user (strided).
// Row elements live in per-thread registers; only (m,S) and the 8 UAs values
// cross threads. Q partials in registers, atomics at the end.
// NEW: grid 512 (2 blocks/CU) + software-pipelined UC-row / UA prefetch so
// the ~900-cycle HBM load latency of user u+stride hides under user u's
// softmax+merge+accumulate phase.
// grid 512 x 256
__global__ __launch_bounds__(256) void k_q(const float* __restrict__ UC,
                                           const float* __restrict__ UA,
                                           float* __restrict__ ws) {
  __shared__ float wm[4], ws4[4], uaS[8];
  int t = threadIdx.x;
  int wid = t >> 6, l = t & 63;
  float rm = 0.f, ris = 0.f;
  if (t < 8) { rm = ws[WS_MK + t]; ris = ws[WS_ISK + t]; }
  float q[8][8];
  #pragma unroll
  for (int j = 0; j < 8; j++)
    #pragma unroll
    for (int k = 0; k < 8; k++) q[j][k] = 0.f;

  // ---- prologue: prefetch first user's row + UA into registers
  int u0 = blockIdx.x;                          // always < U_U (QGRID <= U_U)
  float vcur[8];
  {
    const float* ucrow = UC + (size_t)u0 * 2000;
    #pragma unroll
    for (int j = 0; j < 8; j++) {
      int c = t + 256 * j;
      float v = -INFINITY;
      if (c < 2000) v = __builtin_nontemporal_load(ucrow + c);
      vcur[j] = v;
    }
  }
  float uav = 0.f;
  if (t < 8) uav = UA[(size_t)u0 * 8 + t];

  for (int u = u0; u < U_U; u += QGRID) {
    int un = u + QGRID;
    // ---- issue next user's loads NOW (complete during compute below)
    float vnext[8];
    #pragma unroll
    for (int j = 0; j < 8; j++) {
      int c = t + 256 * j;
      float v = -INFINITY;
      if (un < U_U && c < 2000)
        v = __builtin_nontemporal_load(UC + (size_t)un * 2000 + c);
      vnext[j] = v;
    }
    float uanext = 0.f;
    if (t < 8 && un < U_U) uanext = UA[(size_t)un * 8 + t];

    // ---- per-thread online softmax scan over the 8 register values
    // (same order as the original fused load+scan -> bit-identical)
    float m = -INFINITY, s = 0.f;
    #pragma unroll
    for (int j = 0; j < 8; j++) {
      float v = vcur[j];
      if (v > m) { s = s * __expf(m - v) + 1.f; m = v; }
      else       { s += __expf(v - m); }       // exp(-inf - m) = 0 for pad lanes
    }
    // full-wave online merge (all lanes same user)
    #pragma unroll
    for (int off = 1; off <= 32; off <<= 1) {
      float om = __shfl_xor(m, off), os = __shfl_xor(s, off);
      float M = fmaxf(m, om);
      s = s * __expf(m - M) + os * __expf(om - M);
      m = M;
    }
    if (l == 0) { wm[wid] = m; ws4[wid] = s; }
    if (t < 8) uaS[t] = __expf(uav - rm) * ris;
    __syncthreads();
    float M = fmaxf(fmaxf(wm[0], wm[1]), fmaxf(wm[2], wm[3]));
    float S = ws4[0] * __expf(wm[0] - M) + ws4[1] * __expf(wm[1] - M) +
              ws4[2] * __expf(wm[2] - M) + ws4[3] * __expf(wm[3] - M);
    float inv = 1.f / S;
    float ua[8];
    #pragma unroll
    for (int k = 0; k < 8; k++) ua[k] = uaS[k];
    #pragma unroll
    for (int j = 0; j < 8; j++) {
      int c = t + 256 * j;
      if (c < 2000) {
        float w = __expf(vcur[j] - M) * inv;
        #pragma unroll
        for (int k = 0; k < 8; k++) q[j][k] += w * ua[k];
      }
    }
    __syncthreads();   // wm/ws4/uaS reused next user
    // ---- rotate prefetched registers (dead values if un >= U_U)
    #pragma unroll
    for (int j = 0; j < 8; j++) vcur[j] = vnext[j];
    uav = uanext;
  }
  float* Q = ws + WS_Q;
  #pragma unroll
  for (int j = 0; j < 8; j++) {
    int c = t + 256 * j;
    if (c < 2000) {
      #pragma unroll
      for (int k = 0; k < 8; k++) unsafeAtomicAdd(&Q[c * 8 + k], q[j][k]);
    }
  }
}

// ---------------------------------------------------------------------------
// K5: Y[n,c] = (1 - sig(slide[c]) - sig(guess[c])) * dot8(A[n],Q[c]) + sig(guess[c])
// Block tile: 64 n x 256 c; A tile staged in LDS; nontemporal streaming stores.
// grid (8, 782) x 256
__global__ __launch_bounds__(256) void k_y(const float* __restrict__ guess_,
                                           const float* __restrict__ slide_,
                                           const float* __restrict__ ws,
                                           float* __restrict__ Y) {
  __shared__ float Asm[512];
  int t = threadIdx.x;
  int n0 = blockIdx.y * 64;
  int c = blockIdx.x * 256 + t;
  const float* Aws = ws + WS_A;
  #pragma unroll
  for (int i = 0; i < 2; i++) {
    int idx = t + i * 256;
    int gi = n0 * 8 + idx;
    Asm[idx] = (gi < N_S * 8) ? Aws[gi] : 0.f;
  }
  bool valid = (c < C_C);
  float qv[8] = {0, 0, 0, 0, 0, 0, 0, 0};
  float ac = 0.f, bc = 0.f;
  if (valid) {
    const float* Q = ws + WS_Q;
    #pragma unroll
    for (int k = 0; k < 8; k++) qv[k] = Q[c * 8 + k];
    float sg  = 1.f / (1.f + __expf(-guess_[c]));
    float ssl = 1.f / (1.f + __expf(-slide_[c]));
    ac = 1.f - ssl - sg;
    bc = sg;
  }
  __syncthreads();
  if (!valid) return;
  int nmax = min(64, N_S - n0);
  for (int i = 0; i < nmax; i++) {
    float dot = 0.f;
    #pragma unroll
    for (int k = 0; k < 8; k++) dot += Asm[i * 8 + k] * qv[k];   // LDS broadcast
    float y = fmaf(ac, dot, bc);
    __builtin_nontemporal_store(y, Y + (size_t)(n0 + i) * 2000 + c);
  }
}

// ---------------------------------------------------------------------------
extern "C" void kernel_launch(void* const* d_in, const int* in_sizes, int n_in,
                              void* d_out, int out_size, void* d_ws, size_t ws_size,
                              hipStream_t stream) {
  const float* X      = (const float*)d_in[0];
  const int*   cour   = (const int*)  d_in[1];
  const float* CA     = (const float*)d_in[2];
  const float* UA     = (const float*)d_in[3];
  const float* UC     = (const float*)d_in[4];
  const float* guess_ = (const float*)d_in[5];
  const float* slide_ = (const float*)d_in[6];
  float* Y  = (float*)d_out;
  float* ws = (float*)d_ws;

  hipLaunchKernelGGL(k_ua_part,  dim3(64),      dim3(256), 0, stream, UA, ws);
  hipLaunchKernelGGL(k_ua_final, dim3(1),       dim3(64),  0, stream, ws);
  hipLaunchKernelGGL(k_ca_stats, dim3(4000),    dim3(256), 0, stream, CA, ws);
  hipLaunchKernelGGL(k_act,      dim3(12500),   dim3(256), 0, stream, X, cour, CA, ws);
  hipLaunchKernelGGL(k_q,        dim3(QGRID),   dim3(256), 0, stream, UC, UA, ws);
  hipLaunchKernelGGL(k_y,        dim3(8, 782),  dim3(256), 0, stream, guess_, slide_, ws, Y);
}

// Round 3
// 696.392 us; speedup vs baseline: 1.3361x; 1.3361x over previous
//
#include <hip/hip_runtime.h>
#include <math.h>

// Problem dims (fixed by reference)
#define N_S 50000
#define C_C 2000
#define D_D 128
#define K_K 8
#define U_U 20000

#define QGRID 1024  // k_q blocks: 4 blocks/CU; partials are non-atomic now

typedef float f32x4 __attribute__((ext_vector_type(4)));  // clang vector: OK for nontemporal builtins

// ws layout (float offsets)
#define WS_Q      0          // 16000 floats: Q[c*8+k]
#define WS_P      16384      // 1024: UA online-softmax partials [64 blocks][8 k][m,s]
#define WS_MK     17408      // 8: per-k max of UA column
#define WS_ISK    17416      // 8: per-k 1/sumexp of UA column
#define WS_M      17472      // 16000: per-(c,k) max over d of CA
#define WS_IS     33472      // 16000: per-(c,k) 1/sumexp
#define WS_A      49472      // 400000: A[n*8+k]

// Q partials live in d_out (Y): QGRID * 16000 floats = 65.5 MB << 400 MB.
// Y is dead until k_y, which launches after k_q_red on the same stream.

// ---------------------------------------------------------------------------
// K1a: online column-softmax partials of UA (softmax over U per k)
// grid 64 x 256
__global__ __launch_bounds__(256) void k_ua_part(const float* __restrict__ UA,
                                                 float* __restrict__ ws) {
  int t = threadIdx.x, b = blockIdx.x;
  int gid = b * 256 + t;
  int k = gid & 7;
  float m = -INFINITY, s = 0.f;
  for (int u = (gid >> 3); u < U_U; u += 2048) {
    float v = UA[u * 8 + k];                    // addr = gid + 16384*i: coalesced
    if (v > m) { s = s * __expf(m - v) + 1.f; m = v; }
    else       { s += __expf(v - m); }
  }
  // merge same-k lanes within wave (k = lane&7): xor offsets 8,16,32
  #pragma unroll
  for (int off = 8; off <= 32; off <<= 1) {
    float om = __shfl_xor(m, off);
    float os = __shfl_xor(s, off);
    float M = fmaxf(m, om);
    s = s * __expf(m - M) + os * __expf(om - M);
    m = M;
  }
  __shared__ float sm[32], ss_[32];             // 4 waves x 8 k
  int l = t & 63, wid = t >> 6;
  if (l < 8) { sm[wid * 8 + l] = m; ss_[wid * 8 + l] = s; }
  __syncthreads();
  if (t < 8) {
    float M = sm[t], S = ss_[t];
    #pragma unroll
    for (int w = 1; w < 4; w++) {
      float om = sm[w * 8 + t], os = ss_[w * 8 + t];
      float MM = fmaxf(M, om);
      S = S * __expf(M - MM) + os * __expf(om - MM);
      M = MM;
    }
    ws[WS_P + b * 16 + t * 2]     = M;
    ws[WS_P + b * 16 + t * 2 + 1] = S;
  }
}

// K1b: final merge of 64 UA partials -> m_k, 1/s_k.  grid 1 x 64
__global__ __launch_bounds__(64) void k_ua_final(float* __restrict__ ws) {
  int t = threadIdx.x;
  if (t >= 8) return;
  float M = -INFINITY, S = 0.f;
  for (int b = 0; b < 64; b++) {
    float om = ws[WS_P + b * 16 + t * 2], os = ws[WS_P + b * 16 + t * 2 + 1];
    float MM = fmaxf(M, om);
    S = S * __expf(M - MM) + os * __expf(om - MM);
    M = MM;
  }
  ws[WS_MK + t]  = M;
  ws[WS_ISK + t] = 1.f / S;
}

// ---------------------------------------------------------------------------
// K3: per-(c,k) softmax stats of CA over d (len 128, stride 8 elems).
// One wave per (c,k). grid 4000 x 256
__global__ __launch_bounds__(256) void k_ca_stats(const float* __restrict__ CA,
                                                  float* __restrict__ ws) {
  int t = threadIdx.x;
  int wid = t >> 6, l = t & 63;
  int p = blockIdx.x * 4 + wid;                 // < 16000
  int c = p >> 3, k = p & 7;
  const float* row = CA + (size_t)c * 1024;
  float v0 = row[l * 8 + k];
  float v1 = row[(l + 64) * 8 + k];
  float m = fmaxf(v0, v1);
  #pragma unroll
  for (int off = 1; off <= 32; off <<= 1) m = fmaxf(m, __shfl_xor(m, off));
  float s = __expf(v0 - m) + __expf(v1 - m);
  #pragma unroll
  for (int off = 1; off <= 32; off <<= 1) s += __shfl_xor(s, off);
  if (l == 0) { ws[WS_M + p] = m; ws[WS_IS + p] = 1.f / s; }
}

// ---------------------------------------------------------------------------
// K4: A[n,k] = (1/s_ck) * sum_d X[n,d]*exp(CA[c,d,k]-m_ck), c=cour[n].
// One wave per sample; lane = (dgroup<<3)|k so CA reads are fully coalesced.
// grid 12500 x 256
__global__ __launch_bounds__(256) void k_act(const float* __restrict__ X,
                                             const int* __restrict__ cour,
                                             const float* __restrict__ CA,
                                             float* __restrict__ ws) {
  int t = threadIdx.x;
  int wid = t >> 6, l = t & 63;
  int n = blockIdx.x * 4 + wid;                 // exactly 50000
  int c = cour[n];
  int k = l & 7, dg = l >> 3;
  float mK  = ws[WS_M + c * 8 + k];
  float isK = ws[WS_IS + c * 8 + k];
  const float* carow = CA + (size_t)c * 1024;
  const float* xrow  = X + (size_t)n * 128;
  float acc = 0.f;
  #pragma unroll
  for (int j = 0; j < 16; j++) {
    float v = carow[l + 64 * j];                // 64 consecutive floats / wave-step
    float x = xrow[dg + 8 * j];
    acc += x * __expf(v - mK);
  }
  acc += __shfl_xor(acc, 8);
  acc += __shfl_xor(acc, 16);
  acc += __shfl_xor(acc, 32);
  if (l < 8) ws[WS_A + n * 8 + l] = acc * isK;  // lane l holds k=l
}

// ---------------------------------------------------------------------------
// K2: fused UC row-softmax + Q partial accumulation. One block per user
// (strided). Row elements live in registers; Q partials in registers;
// NON-ATOMIC flush to a private 16000-float slice of QP (= Y scratch).
// Software-pipelined UC-row / UA prefetch hides HBM latency.
// grid 1024 x 256
__global__ __launch_bounds__(256) void k_q(const float* __restrict__ UC,
                                           const float* __restrict__ UA,
                                           float* __restrict__ ws,
                                           float* __restrict__ QP) {
  __shared__ float wm[4], ws4[4], uaS[8];
  int t = threadIdx.x;
  int wid = t >> 6, l = t & 63;
  float rm = 0.f, ris = 0.f;
  if (t < 8) { rm = ws[WS_MK + t]; ris = ws[WS_ISK + t]; }
  float q[8][8];
  #pragma unroll
  for (int j = 0; j < 8; j++)
    #pragma unroll
    for (int k = 0; k < 8; k++) q[j][k] = 0.f;

  // ---- prologue: prefetch first user's row + UA into registers
  int u0 = blockIdx.x;                          // always < U_U (QGRID <= U_U)
  float vcur[8];
  {
    const float* ucrow = UC + (size_t)u0 * 2000;
    #pragma unroll
    for (int j = 0; j < 8; j++) {
      int c = t + 256 * j;
      float v = -INFINITY;
      if (c < 2000) v = __builtin_nontemporal_load(ucrow + c);
      vcur[j] = v;
    }
  }
  float uav = 0.f;
  if (t < 8) uav = UA[(size_t)u0 * 8 + t];

  for (int u = u0; u < U_U; u += QGRID) {
    int un = u + QGRID;
    // ---- issue next user's loads NOW (complete during compute below)
    float vnext[8];
    #pragma unroll
    for (int j = 0; j < 8; j++) {
      int c = t + 256 * j;
      float v = -INFINITY;
      if (un < U_U && c < 2000)
        v = __builtin_nontemporal_load(UC + (size_t)un * 2000 + c);
      vnext[j] = v;
    }
    float uanext = 0.f;
    if (t < 8 && un < U_U) uanext = UA[(size_t)un * 8 + t];

    // ---- per-thread online softmax scan over the 8 register values
    float m = -INFINITY, s = 0.f;
    #pragma unroll
    for (int j = 0; j < 8; j++) {
      float v = vcur[j];
      if (v > m) { s = s * __expf(m - v) + 1.f; m = v; }
      else       { s += __expf(v - m); }       // exp(-inf - m) = 0 for pad lanes
    }
    // full-wave online merge (all lanes same user)
    #pragma unroll
    for (int off = 1; off <= 32; off <<= 1) {
      float om = __shfl_xor(m, off), os = __shfl_xor(s, off);
      float M = fmaxf(m, om);
      s = s * __expf(m - M) + os * __expf(om - M);
      m = M;
    }
    if (l == 0) { wm[wid] = m; ws4[wid] = s; }
    if (t < 8) uaS[t] = __expf(uav - rm) * ris;
    __syncthreads();
    float M = fmaxf(fmaxf(wm[0], wm[1]), fmaxf(wm[2], wm[3]));
    float S = ws4[0] * __expf(wm[0] - M) + ws4[1] * __expf(wm[1] - M) +
              ws4[2] * __expf(wm[2] - M) + ws4[3] * __expf(wm[3] - M);
    float inv = 1.f / S;
    float ua[8];
    #pragma unroll
    for (int k = 0; k < 8; k++) ua[k] = uaS[k];
    #pragma unroll
    for (int j = 0; j < 8; j++) {
      int c = t + 256 * j;
      if (c < 2000) {
        float w = __expf(vcur[j] - M) * inv;
        #pragma unroll
        for (int k = 0; k < 8; k++) q[j][k] += w * ua[k];
      }
    }
    __syncthreads();   // wm/ws4/uaS reused next user
    // ---- rotate prefetched registers (dead values if un >= U_U)
    #pragma unroll
    for (int j = 0; j < 8; j++) vcur[j] = vnext[j];
    uav = uanext;
  }
  // ---- non-atomic flush: block-private slice, fully coalesced 32B/thread
  float* slice = QP + (size_t)blockIdx.x * 16000;
  #pragma unroll
  for (int j = 0; j < 8; j++) {
    int c = t + 256 * j;
    if (c < 2000) {
      f32x4 lo = {q[j][0], q[j][1], q[j][2], q[j][3]};
      f32x4 hi = {q[j][4], q[j][5], q[j][6], q[j][7]};
      __builtin_nontemporal_store(lo, (f32x4*)(slice + c * 8));
      __builtin_nontemporal_store(hi, (f32x4*)(slice + c * 8 + 4));
    }
  }
}

// K2b: reduce QGRID partial slices -> Q[c*8+k]. 16000 floats = 4000 float4.
// grid 16 x 256; thread g sums QP[b][g] (f32x4) over b, 4-way unrolled.
__global__ __launch_bounds__(256) void k_q_red(const float* __restrict__ QP,
                                               float* __restrict__ ws) {
  int g = blockIdx.x * 256 + threadIdx.x;       // float4 index
  if (g >= 4000) return;
  const f32x4* p = (const f32x4*)QP;
  f32x4 a0 = {0.f, 0.f, 0.f, 0.f};
  f32x4 a1 = a0, a2 = a0, a3 = a0;
  #pragma unroll 2
  for (int b = 0; b < QGRID; b += 4) {
    f32x4 v0 = __builtin_nontemporal_load(p + (size_t)(b + 0) * 4000 + g);
    f32x4 v1 = __builtin_nontemporal_load(p + (size_t)(b + 1) * 4000 + g);
    f32x4 v2 = __builtin_nontemporal_load(p + (size_t)(b + 2) * 4000 + g);
    f32x4 v3 = __builtin_nontemporal_load(p + (size_t)(b + 3) * 4000 + g);
    a0 += v0; a1 += v1; a2 += v2; a3 += v3;
  }
  f32x4 r = (a0 + a1) + (a2 + a3);
  ((f32x4*)(ws + WS_Q))[g] = r;
}

// ---------------------------------------------------------------------------
// K5: Y[n,c] = (1 - sig(slide[c]) - sig(guess[c])) * dot8(A[n],Q[c]) + sig(guess[c])
// Block tile: 64 n x 256 c; A tile staged in LDS; nontemporal streaming stores.
// grid (8, 782) x 256
__global__ __launch_bounds__(256) void k_y(const float* __restrict__ guess_,
                                           const float* __restrict__ slide_,
                                           const float* __restrict__ ws,
                                           float* __restrict__ Y) {
  __shared__ float Asm[512];
  int t = threadIdx.x;
  int n0 = blockIdx.y * 64;
  int c = blockIdx.x * 256 + t;
  const float* Aws = ws + WS_A;
  #pragma unroll
  for (int i = 0; i < 2; i++) {
    int idx = t + i * 256;
    int gi = n0 * 8 + idx;
    Asm[idx] = (gi < N_S * 8) ? Aws[gi] : 0.f;
  }
  bool valid = (c < C_C);
  float qv[8] = {0, 0, 0, 0, 0, 0, 0, 0};
  float ac = 0.f, bc = 0.f;
  if (valid) {
    const float* Q = ws + WS_Q;
    #pragma unroll
    for (int k = 0; k < 8; k++) qv[k] = Q[c * 8 + k];
    float sg  = 1.f / (1.f + __expf(-guess_[c]));
    float ssl = 1.f / (1.f + __expf(-slide_[c]));
    ac = 1.f - ssl - sg;
    bc = sg;
  }
  __syncthreads();
  if (!valid) return;
  int nmax = min(64, N_S - n0);
  for (int i = 0; i < nmax; i++) {
    float dot = 0.f;
    #pragma unroll
    for (int k = 0; k < 8; k++) dot += Asm[i * 8 + k] * qv[k];   // LDS broadcast
    float y = fmaf(ac, dot, bc);
    __builtin_nontemporal_store(y, Y + (size_t)(n0 + i) * 2000 + c);
  }
}

// ---------------------------------------------------------------------------
extern "C" void kernel_launch(void* const* d_in, const int* in_sizes, int n_in,
                              void* d_out, int out_size, void* d_ws, size_t ws_size,
                              hipStream_t stream) {
  const float* X      = (const float*)d_in[0];
  const int*   cour   = (const int*)  d_in[1];
  const float* CA     = (const float*)d_in[2];
  const float* UA     = (const float*)d_in[3];
  const float* UC     = (const float*)d_in[4];
  const float* guess_ = (const float*)d_in[5];
  const float* slide_ = (const float*)d_in[6];
  float* Y  = (float*)d_out;
  float* ws = (float*)d_ws;
  float* QP = Y;   // Y (400 MB) is dead until k_y: use as 65.5 MB partial buffer

  hipLaunchKernelGGL(k_ua_part,  dim3(64),      dim3(256), 0, stream, UA, ws);
  hipLaunchKernelGGL(k_ua_final, dim3(1),       dim3(64),  0, stream, ws);
  hipLaunchKernelGGL(k_ca_stats, dim3(4000),    dim3(256), 0, stream, CA, ws);
  hipLaunchKernelGGL(k_act,      dim3(12500),   dim3(256), 0, stream, X, cour, CA, ws);
  hipLaunchKernelGGL(k_q,        dim3(QGRID),   dim3(256), 0, stream, UC, UA, ws, QP);
  hipLaunchKernelGGL(k_q_red,    dim3(16),      dim3(256), 0, stream, QP, ws);
  hipLaunchKernelGGL(k_y,        dim3(8, 782),  dim3(256), 0, stream, guess_, slide_, ws, Y);
}

// Round 4
// 625.018 us; speedup vs baseline: 1.4886x; 1.1142x over previous
//
#include <hip/hip_runtime.h>
#include <math.h>

// Problem dims (fixed by reference)
#define N_S 50000
#define C_C 2000
#define D_D 128
#define K_K 8
#define U_U 20000

#define QGRID 1024  // k_q blocks: 4 blocks/CU; partials are non-atomic
#define RED1_GROUPS 64          // stage-1 slice groups
#define RED1_PER    (QGRID / RED1_GROUPS)   // 16 slices per group

typedef float f32x4 __attribute__((ext_vector_type(4)));  // clang vector: OK for nontemporal builtins

// ws layout (float offsets)
#define WS_Q      0          // 16000 floats: Q[c*8+k]
#define WS_P      16384      // 1024: UA online-softmax partials [64 blocks][8 k][m,s]
#define WS_MK     17408      // 8: per-k max of UA column
#define WS_ISK    17416      // 8: per-k 1/sumexp of UA column
#define WS_M      17472      // 16000: per-(c,k) max over d of CA
#define WS_IS     33472      // 16000: per-(c,k) 1/sumexp
#define WS_A      49472      // 400000: A[n*8+k]

// Q partials live in d_out (Y): QGRID*16000 floats = 65.5 MB, plus 64*16000
// second-level partials at offset 16,384,000. Y (100M floats) is dead until
// k_y, which launches after the reduction on the same stream.
#define QP2_OFF   16384000

// ---------------------------------------------------------------------------
// K1a: online column-softmax partials of UA (softmax over U per k)
// grid 64 x 256
__global__ __launch_bounds__(256) void k_ua_part(const float* __restrict__ UA,
                                                 float* __restrict__ ws) {
  int t = threadIdx.x, b = blockIdx.x;
  int gid = b * 256 + t;
  int k = gid & 7;
  float m = -INFINITY, s = 0.f;
  for (int u = (gid >> 3); u < U_U; u += 2048) {
    float v = UA[u * 8 + k];                    // addr = gid + 16384*i: coalesced
    if (v > m) { s = s * __expf(m - v) + 1.f; m = v; }
    else       { s += __expf(v - m); }
  }
  // merge same-k lanes within wave (k = lane&7): xor offsets 8,16,32
  #pragma unroll
  for (int off = 8; off <= 32; off <<= 1) {
    float om = __shfl_xor(m, off);
    float os = __shfl_xor(s, off);
    float M = fmaxf(m, om);
    s = s * __expf(m - M) + os * __expf(om - M);
    m = M;
  }
  __shared__ float sm[32], ss_[32];             // 4 waves x 8 k
  int l = t & 63, wid = t >> 6;
  if (l < 8) { sm[wid * 8 + l] = m; ss_[wid * 8 + l] = s; }
  __syncthreads();
  if (t < 8) {
    float M = sm[t], S = ss_[t];
    #pragma unroll
    for (int w = 1; w < 4; w++) {
      float om = sm[w * 8 + t], os = ss_[w * 8 + t];
      float MM = fmaxf(M, om);
      S = S * __expf(M - MM) + os * __expf(om - MM);
      M = MM;
    }
    ws[WS_P + b * 16 + t * 2]     = M;
    ws[WS_P + b * 16 + t * 2 + 1] = S;
  }
}

// K1b: final merge of 64 UA partials -> m_k, 1/s_k.  grid 1 x 64
__global__ __launch_bounds__(64) void k_ua_final(float* __restrict__ ws) {
  int t = threadIdx.x;
  if (t >= 8) return;
  float M = -INFINITY, S = 0.f;
  for (int b = 0; b < 64; b++) {
    float om = ws[WS_P + b * 16 + t * 2], os = ws[WS_P + b * 16 + t * 2 + 1];
    float MM = fmaxf(M, om);
    S = S * __expf(M - MM) + os * __expf(om - MM);
    M = MM;
  }
  ws[WS_MK + t]  = M;
  ws[WS_ISK + t] = 1.f / S;
}

// ---------------------------------------------------------------------------
// K3: per-(c,k) softmax stats of CA over d (len 128, stride 8 elems).
// One wave per (c,k). grid 4000 x 256
__global__ __launch_bounds__(256) void k_ca_stats(const float* __restrict__ CA,
                                                  float* __restrict__ ws) {
  int t = threadIdx.x;
  int wid = t >> 6, l = t & 63;
  int p = blockIdx.x * 4 + wid;                 // < 16000
  int c = p >> 3, k = p & 7;
  const float* row = CA + (size_t)c * 1024;
  float v0 = row[l * 8 + k];
  float v1 = row[(l + 64) * 8 + k];
  float m = fmaxf(v0, v1);
  #pragma unroll
  for (int off = 1; off <= 32; off <<= 1) m = fmaxf(m, __shfl_xor(m, off));
  float s = __expf(v0 - m) + __expf(v1 - m);
  #pragma unroll
  for (int off = 1; off <= 32; off <<= 1) s += __shfl_xor(s, off);
  if (l == 0) { ws[WS_M + p] = m; ws[WS_IS + p] = 1.f / s; }
}

// ---------------------------------------------------------------------------
// K4: A[n,k] = (1/s_ck) * sum_d X[n,d]*exp(CA[c,d,k]-m_ck), c=cour[n].
// One wave per sample; lane = (dgroup<<3)|k so CA reads are fully coalesced.
// grid 12500 x 256
__global__ __launch_bounds__(256) void k_act(const float* __restrict__ X,
                                             const int* __restrict__ cour,
                                             const float* __restrict__ CA,
                                             float* __restrict__ ws) {
  int t = threadIdx.x;
  int wid = t >> 6, l = t & 63;
  int n = blockIdx.x * 4 + wid;                 // exactly 50000
  int c = cour[n];
  int k = l & 7, dg = l >> 3;
  float mK  = ws[WS_M + c * 8 + k];
  float isK = ws[WS_IS + c * 8 + k];
  const float* carow = CA + (size_t)c * 1024;
  const float* xrow  = X + (size_t)n * 128;
  float acc = 0.f;
  #pragma unroll
  for (int j = 0; j < 16; j++) {
    float v = carow[l + 64 * j];                // 64 consecutive floats / wave-step
    float x = xrow[dg + 8 * j];
    acc += x * __expf(v - mK);
  }
  acc += __shfl_xor(acc, 8);
  acc += __shfl_xor(acc, 16);
  acc += __shfl_xor(acc, 32);
  if (l < 8) ws[WS_A + n * 8 + l] = acc * isK;  // lane l holds k=l
}

// ---------------------------------------------------------------------------
// K2: fused UC row-softmax + Q partial accumulation. One block per user
// (strided). Row elements live in registers; Q partials in registers;
// NON-ATOMIC flush to a private 16000-float slice of QP (= Y scratch).
// Software-pipelined UC-row / UA prefetch hides HBM latency.
// grid 1024 x 256
__global__ __launch_bounds__(256) void k_q(const float* __restrict__ UC,
                                           const float* __restrict__ UA,
                                           float* __restrict__ ws,
                                           float* __restrict__ QP) {
  __shared__ float wm[4], ws4[4], uaS[8];
  int t = threadIdx.x;
  int wid = t >> 6, l = t & 63;
  float rm = 0.f, ris = 0.f;
  if (t < 8) { rm = ws[WS_MK + t]; ris = ws[WS_ISK + t]; }
  float q[8][8];
  #pragma unroll
  for (int j = 0; j < 8; j++)
    #pragma unroll
    for (int k = 0; k < 8; k++) q[j][k] = 0.f;

  // ---- prologue: prefetch first user's row + UA into registers
  int u0 = blockIdx.x;                          // always < U_U (QGRID <= U_U)
  float vcur[8];
  {
    const float* ucrow = UC + (size_t)u0 * 2000;
    #pragma unroll
    for (int j = 0; j < 8; j++) {
      int c = t + 256 * j;
      float v = -INFINITY;
      if (c < 2000) v = __builtin_nontemporal_load(ucrow + c);
      vcur[j] = v;
    }
  }
  float uav = 0.f;
  if (t < 8) uav = UA[(size_t)u0 * 8 + t];

  for (int u = u0; u < U_U; u += QGRID) {
    int un = u + QGRID;
    // ---- issue next user's loads NOW (complete during compute below)
    float vnext[8];
    #pragma unroll
    for (int j = 0; j < 8; j++) {
      int c = t + 256 * j;
      float v = -INFINITY;
      if (un < U_U && c < 2000)
        v = __builtin_nontemporal_load(UC + (size_t)un * 2000 + c);
      vnext[j] = v;
    }
    float uanext = 0.f;
    if (t < 8 && un < U_U) uanext = UA[(size_t)un * 8 + t];

    // ---- per-thread online softmax scan over the 8 register values
    float m = -INFINITY, s = 0.f;
    #pragma unroll
    for (int j = 0; j < 8; j++) {
      float v = vcur[j];
      if (v > m) { s = s * __expf(m - v) + 1.f; m = v; }
      else       { s += __expf(v - m); }       // exp(-inf - m) = 0 for pad lanes
    }
    // full-wave online merge (all lanes same user)
    #pragma unroll
    for (int off = 1; off <= 32; off <<= 1) {
      float om = __shfl_xor(m, off), os = __shfl_xor(s, off);
      float M = fmaxf(m, om);
      s = s * __expf(m - M) + os * __expf(om - M);
      m = M;
    }
    if (l == 0) { wm[wid] = m; ws4[wid] = s; }
    if (t < 8) uaS[t] = __expf(uav - rm) * ris;
    __syncthreads();
    float M = fmaxf(fmaxf(wm[0], wm[1]), fmaxf(wm[2], wm[3]));
    float S = ws4[0] * __expf(wm[0] - M) + ws4[1] * __expf(wm[1] - M) +
              ws4[2] * __expf(wm[2] - M) + ws4[3] * __expf(wm[3] - M);
    float inv = 1.f / S;
    float ua[8];
    #pragma unroll
    for (int k = 0; k < 8; k++) ua[k] = uaS[k];
    #pragma unroll
    for (int j = 0; j < 8; j++) {
      int c = t + 256 * j;
      if (c < 2000) {
        float w = __expf(vcur[j] - M) * inv;
        #pragma unroll
        for (int k = 0; k < 8; k++) q[j][k] += w * ua[k];
      }
    }
    __syncthreads();   // wm/ws4/uaS reused next user
    // ---- rotate prefetched registers (dead values if un >= U_U)
    #pragma unroll
    for (int j = 0; j < 8; j++) vcur[j] = vnext[j];
    uav = uanext;
  }
  // ---- non-atomic flush: block-private slice, fully coalesced 32B/thread
  float* slice = QP + (size_t)blockIdx.x * 16000;
  #pragma unroll
  for (int j = 0; j < 8; j++) {
    int c = t + 256 * j;
    if (c < 2000) {
      f32x4 lo = {q[j][0], q[j][1], q[j][2], q[j][3]};
      f32x4 hi = {q[j][4], q[j][5], q[j][6], q[j][7]};
      __builtin_nontemporal_store(lo, (f32x4*)(slice + c * 8));
      __builtin_nontemporal_store(hi, (f32x4*)(slice + c * 8 + 4));
    }
  }
}

// K2b stage 1: sum 16 slices per (slice-group, float4-column).
// grid (16, 64) x 256: x covers g in [0,4000), y = slice group.
// 1024 blocks spread over all CUs -> BW-bound (~15 us for 65.5 MB).
__global__ __launch_bounds__(256) void k_q_red1(const float* __restrict__ QP,
                                                float* __restrict__ QP2) {
  int g = blockIdx.x * 256 + threadIdx.x;       // float4 index
  if (g >= 4000) return;
  int y = blockIdx.y;
  const f32x4* p = (const f32x4*)QP + (size_t)(y * RED1_PER) * 4000 + g;
  f32x4 a0 = {0.f, 0.f, 0.f, 0.f};
  f32x4 a1 = a0, a2 = a0, a3 = a0;
  #pragma unroll
  for (int b = 0; b < RED1_PER; b += 4) {
    f32x4 v0 = __builtin_nontemporal_load(p + (size_t)(b + 0) * 4000);
    f32x4 v1 = __builtin_nontemporal_load(p + (size_t)(b + 1) * 4000);
    f32x4 v2 = __builtin_nontemporal_load(p + (size_t)(b + 2) * 4000);
    f32x4 v3 = __builtin_nontemporal_load(p + (size_t)(b + 3) * 4000);
    a0 += v0; a1 += v1; a2 += v2; a3 += v3;
  }
  f32x4 r = (a0 + a1) + (a2 + a3);
  ((f32x4*)QP2)[(size_t)y * 4000 + g] = r;
}

// K2b stage 2: sum the 64 group partials -> Q. grid 16 x 256 (4 MB read).
__global__ __launch_bounds__(256) void k_q_red2(const float* __restrict__ QP2,
                                                float* __restrict__ ws) {
  int g = blockIdx.x * 256 + threadIdx.x;       // float4 index
  if (g >= 4000) return;
  const f32x4* p = (const f32x4*)QP2;
  f32x4 a0 = {0.f, 0.f, 0.f, 0.f};
  f32x4 a1 = a0, a2 = a0, a3 = a0;
  #pragma unroll
  for (int b = 0; b < RED1_GROUPS; b += 4) {
    f32x4 v0 = p[(size_t)(b + 0) * 4000 + g];
    f32x4 v1 = p[(size_t)(b + 1) * 4000 + g];
    f32x4 v2 = p[(size_t)(b + 2) * 4000 + g];
    f32x4 v3 = p[(size_t)(b + 3) * 4000 + g];
    a0 += v0; a1 += v1; a2 += v2; a3 += v3;
  }
  f32x4 r = (a0 + a1) + (a2 + a3);
  ((f32x4*)(ws + WS_Q))[g] = r;
}

// ---------------------------------------------------------------------------
// K5: Y[n,c] = (1 - sig(slide[c]) - sig(guess[c])) * dot8(A[n],Q[c]) + sig(guess[c])
// Block tile: 64 n x 256 c; A tile staged in LDS; nontemporal streaming stores.
// grid (8, 782) x 256
__global__ __launch_bounds__(256) void k_y(const float* __restrict__ guess_,
                                           const float* __restrict__ slide_,
                                           const float* __restrict__ ws,
                                           float* __restrict__ Y) {
  __shared__ float Asm[512];
  int t = threadIdx.x;
  int n0 = blockIdx.y * 64;
  int c = blockIdx.x * 256 + t;
  const float* Aws = ws + WS_A;
  #pragma unroll
  for (int i = 0; i < 2; i++) {
    int idx = t + i * 256;
    int gi = n0 * 8 + idx;
    Asm[idx] = (gi < N_S * 8) ? Aws[gi] : 0.f;
  }
  bool valid = (c < C_C);
  float qv[8] = {0, 0, 0, 0, 0, 0, 0, 0};
  float ac = 0.f, bc = 0.f;
  if (valid) {
    const float* Q = ws + WS_Q;
    #pragma unroll
    for (int k = 0; k < 8; k++) qv[k] = Q[c * 8 + k];
    float sg  = 1.f / (1.f + __expf(-guess_[c]));
    float ssl = 1.f / (1.f + __expf(-slide_[c]));
    ac = 1.f - ssl - sg;
    bc = sg;
  }
  __syncthreads();
  if (!valid) return;
  int nmax = min(64, N_S - n0);
  for (int i = 0; i < nmax; i++) {
    float dot = 0.f;
    #pragma unroll
    for (int k = 0; k < 8; k++) dot += Asm[i * 8 + k] * qv[k];   // LDS broadcast
    float y = fmaf(ac, dot, bc);
    __builtin_nontemporal_store(y, Y + (size_t)(n0 + i) * 2000 + c);
  }
}

// ---------------------------------------------------------------------------
extern "C" void kernel_launch(void* const* d_in, const int* in_sizes, int n_in,
                              void* d_out, int out_size, void* d_ws, size_t ws_size,
                              hipStream_t stream) {
  const float* X      = (const float*)d_in[0];
  const int*   cour   = (const int*)  d_in[1];
  const float* CA     = (const float*)d_in[2];
  const float* UA     = (const float*)d_in[3];
  const float* UC     = (const float*)d_in[4];
  const float* guess_ = (const float*)d_in[5];
  const float* slide_ = (const float*)d_in[6];
  float* Y   = (float*)d_out;
  float* ws  = (float*)d_ws;
  float* QP  = Y;              // 65.5 MB of Y used as partial buffer
  float* QP2 = Y + QP2_OFF;    // 4 MB second-level partials

  hipLaunchKernelGGL(k_ua_part,  dim3(64),       dim3(256), 0, stream, UA, ws);
  hipLaunchKernelGGL(k_ua_final, dim3(1),        dim3(64),  0, stream, ws);
  hipLaunchKernelGGL(k_ca_stats, dim3(4000),     dim3(256), 0, stream, CA, ws);
  hipLaunchKernelGGL(k_act,      dim3(12500),    dim3(256), 0, stream, X, cour, CA, ws);
  hipLaunchKernelGGL(k_q,        dim3(QGRID),    dim3(256), 0, stream, UC, UA, ws, QP);
  hipLaunchKernelGGL(k_q_red1,   dim3(16, 64),   dim3(256), 0, stream, QP, QP2);
  hipLaunchKernelGGL(k_q_red2,   dim3(16),       dim3(256), 0, stream, QP2, ws);
  hipLaunchKernelGGL(k_y,        dim3(8, 782),   dim3(256), 0, stream, guess_, slide_, ws, Y);
}